// Round 9
// baseline (696.020 us; speedup 1.0000x reference)
//
#include <hip/hip_runtime.h>

#define NNODES 50000
#define NEDGES 800000
#define NTILES ((NNODES + 255) / 256)   // 196

typedef unsigned short ushort_t;
typedef __attribute__((ext_vector_type(8))) short short8;
typedef __attribute__((ext_vector_type(4))) float floatx4;

__device__ __forceinline__ float bf2f(unsigned short u) {
  union { unsigned int i; float f; } v; v.i = ((unsigned int)u) << 16; return v.f;
}
__device__ __forceinline__ unsigned short f2bf(float f) {
  union { float f; unsigned int i; } v; v.f = f;
  unsigned int r = v.i + 0x7fffu + ((v.i >> 16) & 1u);
  return (unsigned short)(r >> 16);
}

__device__ __forceinline__ void gload_lds16(const void* g, void* l) {
  __builtin_amdgcn_global_load_lds(
      (const __attribute__((address_space(1))) unsigned int*)g,
      (__attribute__((address_space(3))) unsigned int*)l, 16, 0, 0);
}

// ---------------- graph preprocessing ----------------

__global__ void hist_kernel(const int* dst, int* cnt) {
  int i = blockIdx.x * 256 + threadIdx.x;
  if (i < NEDGES) atomicAdd(&cnt[dst[i]], 1);
}

__global__ __launch_bounds__(256) void tile_scan_kernel(
    const int* __restrict__ cnt, int* __restrict__ tile_pref, int* __restrict__ tile_sum) {
  __shared__ int s[256];
  int b = blockIdx.x, t = threadIdx.x;
  int i = b * 256 + t;
  int v = (i < NNODES) ? cnt[i] : 0;
  s[t] = v;
  __syncthreads();
#pragma unroll
  for (int off = 1; off < 256; off <<= 1) {
    int x = (t >= off) ? s[t - off] : 0;
    __syncthreads();
    s[t] += x;
    __syncthreads();
  }
  if (i < NNODES) tile_pref[i] = s[t] - v;   // exclusive within tile
  if (t == 255) tile_sum[b] = s[255];
}

__global__ __launch_bounds__(256) void sum_scan_kernel(
    const int* __restrict__ tile_sum, int* __restrict__ tile_base) {
  __shared__ int s[256];
  int t = threadIdx.x;
  int v = (t < NTILES) ? tile_sum[t] : 0;
  s[t] = v;
  __syncthreads();
#pragma unroll
  for (int off = 1; off < 256; off <<= 1) {
    int x = (t >= off) ? s[t - off] : 0;
    __syncthreads();
    s[t] += x;
    __syncthreads();
  }
  if (t < NTILES) tile_base[t] = s[t] - v;   // exclusive across tiles
}

// also computes dinv (fused)
__global__ __launch_bounds__(256) void scan_write_kernel(
    const int* __restrict__ cnt, const int* __restrict__ tile_pref,
    const int* __restrict__ tile_base, int* __restrict__ row_ptr,
    int* __restrict__ cursor, float* __restrict__ dinv) {
  int b = blockIdx.x, t = threadIdx.x;
  int i = b * 256 + t;
  if (i < NNODES) {
    int base = tile_base[b] + tile_pref[i];
    row_ptr[i] = base;
    cursor[i] = base;
    dinv[i] = rsqrtf((float)(cnt[i] + 1));  // +1 self loop
    if (i == NNODES - 1) row_ptr[NNODES] = base + cnt[i];
  }
}

__global__ void fill_kernel(const int* src, const int* dst, int* cursor, int* col_idx) {
  int i = blockIdx.x * 256 + threadIdx.x;
  if (i < NEDGES) {
    int p = atomicAdd(&cursor[dst[i]], 1);
    col_idx[p] = src[i];
  }
}

// -------- weight prep (all 5 weights, one kernel): transpose + bf16 hi/lo --------
__global__ void wprep_all(
    const float* __restrict__ W1, const float* __restrict__ W2,
    const float* __restrict__ W3, const float* __restrict__ W4,
    const float* __restrict__ Wl,
    ushort_t* W1h, ushort_t* W1l, ushort_t* W2h, ushort_t* W2l,
    ushort_t* W3h, ushort_t* W3l, ushort_t* W4h, ushort_t* W4l,
    ushort_t* Wlh, ushort_t* Wll) {
  int idx = blockIdx.x * 256 + threadIdx.x;
  const float* W; ushort_t* ph; ushort_t* pl; int K, N, base;
  if (idx < 49152)       { W = W1; ph = W1h; pl = W1l; K = 384; N = 128; base = 0; }
  else if (idx < 98304)  { W = W2; ph = W2h; pl = W2l; K = 128; N = 384; base = 49152; }
  else if (idx < 196608) { W = W3; ph = W3h; pl = W3l; K = 384; N = 256; base = 98304; }
  else if (idx < 294912) { W = W4; ph = W4h; pl = W4l; K = 256; N = 384; base = 196608; }
  else if (idx < 344064) { W = Wl; ph = Wlh; pl = Wll; K = 384; N = 128; base = 294912; }
  else return;
  int i = idx - base;
  int n = i / K, k = i - n * K;
  float w = W[(size_t)k * N + n];
  unsigned short h = f2bf(w);
  ph[i] = h;
  pl[i] = f2bf(w - bf2f(h));
}

// ---------------- chunked aggregation ----------------
// Gather input laid out [chunk][NNODES][32 cols] (64 B per node per chunk) so
// each chunk's working set (3.2 MB) fits in one XCD's 4 MB L2.
// 16 threads per node (2 cols each), 16 nodes per 256-thr block, grid.y=chunks.
// Input values PRE-SCALED by source dinv.
// mode 0: out = di*sum ; mode 1: out = leaky(di*sum + bias) [*di if scale_store]
__global__ __launch_bounds__(256) void agg_chunked(
    const ushort_t* __restrict__ in, ushort_t* __restrict__ out,
    const int* __restrict__ row_ptr, const int* __restrict__ col_idx,
    const float* __restrict__ dinv, const float* __restrict__ bias,
    int W, int mode, int scale_store, int out_chunked) {
  int t = threadIdx.x;
  int node = blockIdx.x * 16 + (t >> 4);
  if (node >= NNODES) return;
  int cp = t & 15;                       // col-pair within chunk
  int chunk = blockIdx.y;
  int col = chunk * 32 + cp * 2;
  const ushort_t* cbase = in + (size_t)chunk * NNODES * 32 + cp * 2;
  unsigned int u = *(const unsigned int*)(cbase + (size_t)node * 32);
  float a0 = bf2f((unsigned short)(u & 0xffff));
  float a1 = bf2f((unsigned short)(u >> 16));
  int e = row_ptr[node], e1 = row_ptr[node + 1];
  for (; e + 8 <= e1; e += 8) {
    unsigned int uu[8];
#pragma unroll
    for (int q = 0; q < 8; ++q) {
      int j = col_idx[e + q];
      uu[q] = *(const unsigned int*)(cbase + (size_t)j * 32);
    }
#pragma unroll
    for (int q = 0; q < 8; ++q) {
      a0 += bf2f((unsigned short)(uu[q] & 0xffff));
      a1 += bf2f((unsigned short)(uu[q] >> 16));
    }
  }
  for (; e < e1; ++e) {
    int j = col_idx[e];
    unsigned int uu = *(const unsigned int*)(cbase + (size_t)j * 32);
    a0 += bf2f((unsigned short)(uu & 0xffff));
    a1 += bf2f((unsigned short)(uu >> 16));
  }
  float di = dinv[node];
  a0 *= di; a1 *= di;
  if (mode) {
    float2 bb = *(const float2*)(bias + col);
    a0 += bb.x; a1 += bb.y;
    a0 = a0 > 0.f ? a0 : 0.01f * a0;
    a1 = a1 > 0.f ? a1 : 0.01f * a1;
    if (scale_store) { a0 *= di; a1 *= di; }
  }
  unsigned int o = (unsigned int)f2bf(a0) | ((unsigned int)f2bf(a1) << 16);
  if (out_chunked)
    *(unsigned int*)(out + (size_t)chunk * NNODES * 32 + (size_t)node * 32 + cp * 2) = o;
  else
    *(unsigned int*)(out + (size_t)node * W + col) = o;
}

// ---------------- MFMA GEMM: C = A[M,K] @ (Bhi+Blo)[N,K]^T ----------------
// TBM x TBN tile, BK=32, 4 waves (2x2), 16x16x32 bf16 MFMA, hi/lo split
// weights (f32-accurate). global_load_lds(16B) staging for bf16 A/B; a_f32
// converts f32->bf16 in-register. mode 0: raw; 1: +bias leaky; 2: +bias relu.
// scale_store: *dinv[row]. out_mode: 0 bf16 row-major, 1 f32 row-major,
// 2 bf16 chunk-major ([col/32][NNODES][32]).

#define BK 32

template <int TBM, int TBN>
__global__ __launch_bounds__(256, TBM == 64 ? 6 : 4) void gemm_mfma(
    const void* __restrict__ Av, const ushort_t* __restrict__ Bhi,
    const ushort_t* __restrict__ Blo, void* __restrict__ Cv,
    const float* __restrict__ bias, const float* __restrict__ dinv,
    int M, int K, int ldc, int mode, int scale_store, int out_mode, int a_f32) {
  constexpr int FR = TBM / 32;
  constexpr int FG = TBN / 32;
  constexpr int AIT = TBM / 64;
  constexpr int BIT = TBN / 64;
  __shared__ ushort_t As[TBM * BK];
  __shared__ ushort_t Bh[TBN * BK];
  __shared__ ushort_t Bl[TBN * BK];
  int tid = threadIdx.x;
  int lane = tid & 63, w = tid >> 6;
  int wm = w & 1, wn = w >> 1;
  int m0 = blockIdx.x * TBM, n0 = blockIdx.y * TBN;
  floatx4 acc[FR][FG] = {};
  int nkt = K / BK;
  for (int kt = 0; kt < nkt; ++kt) {
    int kb = kt * BK;
    uint4 va[AIT];
    if (a_f32) {
      const float* Af = (const float*)Av;
#pragma unroll
      for (int it = 0; it < AIT; ++it) {
        int s = it * 256 + tid;
        int row = s >> 2, ks = (s & 3) * 8;
        int gr = m0 + row; if (gr > M - 1) gr = M - 1;
        float4 p0 = *(const float4*)(Af + (size_t)gr * K + kb + ks);
        float4 p1 = *(const float4*)(Af + (size_t)gr * K + kb + ks + 4);
        uint4 u;
        u.x = (unsigned int)f2bf(p0.x) | ((unsigned int)f2bf(p0.y) << 16);
        u.y = (unsigned int)f2bf(p0.z) | ((unsigned int)f2bf(p0.w) << 16);
        u.z = (unsigned int)f2bf(p1.x) | ((unsigned int)f2bf(p1.y) << 16);
        u.w = (unsigned int)f2bf(p1.z) | ((unsigned int)f2bf(p1.w) << 16);
        va[it] = u;
      }
    }
    __syncthreads();  // previous iteration's LDS reads complete
    if (a_f32) {
#pragma unroll
      for (int it = 0; it < AIT; ++it) {
        int s = it * 256 + tid;
        *(uint4*)&As[s * 8] = va[it];
      }
    } else {
#pragma unroll
      for (int it = 0; it < AIT; ++it) {
        int s = it * 256 + tid;
        int row = s >> 2, ks = (s & 3) * 8;
        int gr = m0 + row; if (gr > M - 1) gr = M - 1;  // clamp; stores guarded
        gload_lds16((const ushort_t*)Av + (size_t)gr * K + kb + ks,
                    As + (size_t)(it * 256 + w * 64) * 8);
      }
    }
#pragma unroll
    for (int it = 0; it < BIT; ++it) {
      int s = it * 256 + tid;
      int row = s >> 2, ks = (s & 3) * 8;
      gload_lds16(Bhi + (size_t)(n0 + row) * K + kb + ks,
                  Bh + (size_t)(it * 256 + w * 64) * 8);
      gload_lds16(Blo + (size_t)(n0 + row) * K + kb + ks,
                  Bl + (size_t)(it * 256 + w * 64) * 8);
    }
    __syncthreads();  // drains vmcnt (incl. LDS-DMA) and lgkm
    short8 af[FR], fh[FG], fl[FG];
#pragma unroll
    for (int f = 0; f < FR; ++f)
      af[f] = *(const short8*)&As[(wm * (TBM / 2) + f * 16 + (lane & 15)) * BK + (lane >> 4) * 8];
#pragma unroll
    for (int g = 0; g < FG; ++g) {
      int o = (wn * (TBN / 2) + g * 16 + (lane & 15)) * BK + (lane >> 4) * 8;
      fh[g] = *(const short8*)&Bh[o];
      fl[g] = *(const short8*)&Bl[o];
    }
#pragma unroll
    for (int f = 0; f < FR; ++f)
#pragma unroll
      for (int g = 0; g < FG; ++g) {
        acc[f][g] = __builtin_amdgcn_mfma_f32_16x16x32_bf16(af[f], fh[g], acc[f][g], 0, 0, 0);
        acc[f][g] = __builtin_amdgcn_mfma_f32_16x16x32_bf16(af[f], fl[g], acc[f][g], 0, 0, 0);
      }
  }
  int cr = lane >> 4, cc = lane & 15;
#pragma unroll
  for (int f = 0; f < FR; ++f) {
#pragma unroll
    for (int r = 0; r < 4; ++r) {
      int row = m0 + wm * (TBM / 2) + f * 16 + cr * 4 + r;
      if (row >= M) continue;
      float sc = scale_store ? dinv[row] : 1.f;
#pragma unroll
      for (int g = 0; g < FG; ++g) {
        int col = n0 + wn * (TBN / 2) + g * 16 + cc;
        float v = acc[f][g][r];
        if (mode) {
          v += bias[col];
          v = (mode == 1) ? (v > 0.f ? v : 0.01f * v) : (v > 0.f ? v : 0.f);
        }
        v *= sc;
        if (out_mode == 1) ((float*)Cv)[(size_t)row * ldc + col] = v;
        else if (out_mode == 2)
          ((ushort_t*)Cv)[((size_t)(col >> 5) * NNODES + row) * 32 + (col & 31)] = f2bf(v);
        else ((ushort_t*)Cv)[(size_t)row * ldc + col] = f2bf(v);
      }
    }
  }
}

// ---------------- driver ----------------

extern "C" void kernel_launch(void* const* d_in, const int* in_sizes, int n_in,
                              void* d_out, int out_size, void* d_ws, size_t ws_size,
                              hipStream_t stream) {
  const float* x  = (const float*)d_in[0];
  const int* ei   = (const int*)d_in[1];
  const float* W1 = (const float*)d_in[2];
  const float* b1 = (const float*)d_in[3];
  const float* W2 = (const float*)d_in[4];
  const float* b2 = (const float*)d_in[5];
  const float* W3 = (const float*)d_in[6];
  const float* b3 = (const float*)d_in[7];
  const float* W4 = (const float*)d_in[8];
  const float* b4 = (const float*)d_in[9];
  const float* Wl = (const float*)d_in[10];
  const float* bl = (const float*)d_in[11];

  char* p = (char*)d_ws;
  auto alloc = [&](size_t bytes) {
    char* r = p;
    p += (bytes + 255) & ~(size_t)255;
    return r;
  };
  int* cnt       = (int*)alloc((size_t)NNODES * 4);
  int* cursor    = (int*)alloc((size_t)NNODES * 4);
  int* row_ptr   = (int*)alloc((size_t)(NNODES + 1) * 4);
  float* dinv    = (float*)alloc((size_t)NNODES * 4);
  int* col_idx   = (int*)alloc((size_t)NEDGES * 4);
  int* tile_pref = (int*)alloc((size_t)NNODES * 4);
  int* tile_sum  = (int*)alloc(256 * 4);
  int* tile_base = (int*)alloc(256 * 4);
  ushort_t* W1h = (ushort_t*)alloc(49152 * 2); ushort_t* W1l = (ushort_t*)alloc(49152 * 2);
  ushort_t* W2h = (ushort_t*)alloc(49152 * 2); ushort_t* W2l = (ushort_t*)alloc(49152 * 2);
  ushort_t* W3h = (ushort_t*)alloc(98304 * 2); ushort_t* W3l = (ushort_t*)alloc(98304 * 2);
  ushort_t* W4h = (ushort_t*)alloc(98304 * 2); ushort_t* W4l = (ushort_t*)alloc(98304 * 2);
  ushort_t* Wlh = (ushort_t*)alloc(49152 * 2); ushort_t* Wll = (ushort_t*)alloc(49152 * 2);
  ushort_t* actA = (ushort_t*)alloc((size_t)NNODES * 384 * 2);
  ushort_t* actB = (ushort_t*)alloc((size_t)NNODES * 384 * 2);

  const int* src = ei;
  const int* dst = ei + NEDGES;

  hipMemsetAsync(cnt, 0, (size_t)NNODES * 4, stream);
  hist_kernel<<<(NEDGES + 255) / 256, 256, 0, stream>>>(dst, cnt);
  tile_scan_kernel<<<NTILES, 256, 0, stream>>>(cnt, tile_pref, tile_sum);
  sum_scan_kernel<<<1, 256, 0, stream>>>(tile_sum, tile_base);
  scan_write_kernel<<<NTILES, 256, 0, stream>>>(cnt, tile_pref, tile_base, row_ptr, cursor, dinv);
  fill_kernel<<<(NEDGES + 255) / 256, 256, 0, stream>>>(src, dst, cursor, col_idx);
  wprep_all<<<(344064 + 255) / 256, 256, 0, stream>>>(
      W1, W2, W3, W4, Wl, W1h, W1l, W2h, W2l, W3h, W3l, W4h, W4l, Wlh, Wll);

  dim3 blk(256);
  int gm64  = (NNODES + 63) / 64;    // 782
  int gm128 = (NNODES + 127) / 128;  // 391
  int gagg  = NNODES / 16;           // 3125

  // L1 (384->128): gemm reads x f32 (chunk-major, pre-scaled store)
  gemm_mfma<64, 64><<<dim3(gm64, 2), blk, 0, stream>>>(x, W1h, W1l, actA, (const float*)0, dinv, NNODES, 384, 128, 0, 1, 2, 1);
  // agg1: +b1 leaky, pre-scaled, chunk-major out
  agg_chunked<<<dim3(gagg, 4), blk, 0, stream>>>(actA, actB, row_ptr, col_idx, dinv, b1, 128, 1, 1, 1);
  // agg2: plain, row-major out (A of L2 gemm)
  agg_chunked<<<dim3(gagg, 4), blk, 0, stream>>>(actB, actA, row_ptr, col_idx, dinv, (const float*)0, 128, 0, 0, 0);
  // L2 (128->384): gemm(+b2, leaky), bf16 row-major
  gemm_mfma<128, 128><<<dim3(gm128, 3), blk, 0, stream>>>(actA, W2h, W2l, actB, b2, dinv, NNODES, 128, 384, 1, 0, 0, 0);
  // L3 (384->256): gemm, chunk-major pre-scaled store
  gemm_mfma<128, 128><<<dim3(gm128, 2), blk, 0, stream>>>(actB, W3h, W3l, actA, (const float*)0, dinv, NNODES, 384, 256, 0, 1, 2, 0);
  // agg3: +b3 leaky, pre-scaled, chunk-major out
  agg_chunked<<<dim3(gagg, 8), blk, 0, stream>>>(actA, actB, row_ptr, col_idx, dinv, b3, 256, 1, 1, 1);
  // agg4: plain, row-major out (A of L4 gemm)
  agg_chunked<<<dim3(gagg, 8), blk, 0, stream>>>(actB, actA, row_ptr, col_idx, dinv, (const float*)0, 256, 0, 0, 0);
  // L4 (256->384): gemm(+b4, leaky), bf16 row-major
  gemm_mfma<128, 128><<<dim3(gm128, 3), blk, 0, stream>>>(actA, W4h, W4l, actB, b4, dinv, NNODES, 256, 384, 1, 0, 0, 0);
  // final linear (384->128) + relu -> d_out (f32)
  gemm_mfma<64, 64><<<dim3(gm64, 2), blk, 0, stream>>>(actB, Wlh, Wll, d_out, bl, dinv, NNODES, 384, 128, 2, 0, 1, 0);
}